// Round 1
// baseline (313.668 us; speedup 1.0000x reference)
//
#include <hip/hip_runtime.h>

#define BB 32
#define NN 2048
#define HH 512

static __device__ __forceinline__ float dot4(float4 a, float4 b) {
    return a.x * b.x + a.y * b.y + a.z * b.z + a.w * b.w;
}

// ws layout (floats): u0[0,16384) u1[16384,32768) scores[32768,98304)
// No ws zeroing needed anymore: scores fully written by k_scores before use;
// u0/u1 exclusively owned+written by k_wsum h-chunks (no atomics) — poison-safe.

// Kernel 1: scores[b,n] = adj ? K[b,n]·wk : -1e30 (raw).
// Softmax is shift-invariant so Q·wq + b_att cancels exactly — dropped.
// 4 rows per wave: wk loaded once, 8 independent K float4 loads in flight.
__global__ void k_scores(const float* __restrict__ K,
                         const float* __restrict__ w_att,
                         const int* __restrict__ adj,
                         float* __restrict__ scores) {
    int wave = (blockIdx.x * blockDim.x + threadIdx.x) >> 6;
    int lane = threadIdx.x & 63;
    const float* wk = w_att + HH;
    float4 a0 = *(const float4*)(wk + lane * 4);
    float4 a1 = *(const float4*)(wk + 256 + lane * 4);
    int row0 = wave * 4;  // wave < BB*NN/4 by grid construction
    const float* Kb = K + (size_t)row0 * HH + lane * 4;
    float4 k00 = *(const float4*)(Kb);
    float4 k01 = *(const float4*)(Kb + 256);
    float4 k10 = *(const float4*)(Kb + HH);
    float4 k11 = *(const float4*)(Kb + HH + 256);
    float4 k20 = *(const float4*)(Kb + 2 * HH);
    float4 k21 = *(const float4*)(Kb + 2 * HH + 256);
    float4 k30 = *(const float4*)(Kb + 3 * HH);
    float4 k31 = *(const float4*)(Kb + 3 * HH + 256);
    float s0 = dot4(k00, a0) + dot4(k01, a1);
    float s1 = dot4(k10, a0) + dot4(k11, a1);
    float s2 = dot4(k20, a0) + dot4(k21, a1);
    float s3 = dot4(k30, a0) + dot4(k31, a1);
#pragma unroll
    for (int off = 32; off > 0; off >>= 1) {
        s0 += __shfl_down(s0, off, 64);
        s1 += __shfl_down(s1, off, 64);
        s2 += __shfl_down(s2, off, 64);
        s3 += __shfl_down(s3, off, 64);
    }
    if (lane == 0) {
        int4 a = *(const int4*)(adj + row0);
        float4 o;
        o.x = a.x ? s0 : -1e30f;
        o.y = a.y ? s1 : -1e30f;
        o.z = a.z ? s2 : -1e30f;
        o.w = a.w ? s3 : -1e30f;
        *(float4*)(scores + row0) = o;
    }
}

// Kernel 2: h-partitioned weighted-V accumulation, NO atomics.
// grid = B * (H/16) = 1024 blocks x 256 threads. Block (b, hc) owns
// u0/u1[b, hc:hc+16] exclusively: sums attn-weighted V over all 2048 rows.
// Softmax stats recomputed per block from L2-resident scores (8 KB/block).
#define CH 16
__global__ void k_wsum(const float* __restrict__ V,
                       const float* __restrict__ scores,
                       float* __restrict__ attn,
                       const int* __restrict__ s_mask,
                       float* __restrict__ u0,
                       float* __restrict__ u1) {
    int b = blockIdx.x >> 5;
    int hc = (blockIdx.x & 31) * CH;
    int t = threadIdx.x;
    __shared__ float red[4];
    __shared__ float2 wls[NN];       // 16 KB: {w*sm, w*(1-sm)} per row
    __shared__ float part[4][4][8];  // [wave][col][8] cross-wave reduce

    // --- softmax stats over the full batch row (vectorized, registers) ---
    const float* srow = scores + b * NN;
    float4 va = *(const float4*)(srow + t * 8);
    float4 vb = *(const float4*)(srow + t * 8 + 4);
    float m = fmaxf(fmaxf(fmaxf(va.x, va.y), fmaxf(va.z, va.w)),
                    fmaxf(fmaxf(vb.x, vb.y), fmaxf(vb.z, vb.w)));
#pragma unroll
    for (int off = 32; off > 0; off >>= 1) m = fmaxf(m, __shfl_xor(m, off, 64));
    if ((t & 63) == 0) red[t >> 6] = m;
    __syncthreads();
    float m4 = fmaxf(fmaxf(red[0], red[1]), fmaxf(red[2], red[3]));
    float e0 = expf(va.x - m4), e1 = expf(va.y - m4);
    float e2 = expf(va.z - m4), e3 = expf(va.w - m4);
    float e4 = expf(vb.x - m4), e5 = expf(vb.y - m4);
    float e6 = expf(vb.z - m4), e7 = expf(vb.w - m4);
    float sum = ((e0 + e1) + (e2 + e3)) + ((e4 + e5) + (e6 + e7));
#pragma unroll
    for (int off = 32; off > 0; off >>= 1) sum += __shfl_xor(sum, off, 64);
    __syncthreads();  // red reuse
    if ((t & 63) == 0) red[t >> 6] = sum;
    __syncthreads();
    float inv = 1.0f / (red[0] + red[1] + red[2] + red[3]);

    // --- normalized weights: attn output (chunk 0 only) + LDS staging ---
    float w0 = e0 * inv, w1 = e1 * inv, w2 = e2 * inv, w3 = e3 * inv;
    float w4 = e4 * inv, w5 = e5 * inv, w6 = e6 * inv, w7 = e7 * inv;
    if (hc == 0) {
        float4 oa = {w0, w1, w2, w3};
        float4 ob = {w4, w5, w6, w7};
        *(float4*)(attn + b * NN + t * 8) = oa;
        *(float4*)(attn + b * NN + t * 8 + 4) = ob;
    }
    int4 sa = *(const int4*)(s_mask + b * NN + t * 8);
    int4 sb = *(const int4*)(s_mask + b * NN + t * 8 + 4);
    int i8 = t * 8;
    wls[i8 + 0] = sa.x ? make_float2(w0, 0.f) : make_float2(0.f, w0);
    wls[i8 + 1] = sa.y ? make_float2(w1, 0.f) : make_float2(0.f, w1);
    wls[i8 + 2] = sa.z ? make_float2(w2, 0.f) : make_float2(0.f, w2);
    wls[i8 + 3] = sa.w ? make_float2(w3, 0.f) : make_float2(0.f, w3);
    wls[i8 + 4] = sb.x ? make_float2(w4, 0.f) : make_float2(0.f, w4);
    wls[i8 + 5] = sb.y ? make_float2(w5, 0.f) : make_float2(0.f, w5);
    wls[i8 + 6] = sb.z ? make_float2(w6, 0.f) : make_float2(0.f, w6);
    wls[i8 + 7] = sb.w ? make_float2(w7, 0.f) : make_float2(0.f, w7);
    __syncthreads();

    // --- weighted V accumulation over all rows for this 16-col slice ---
    // thread t: col = t&3 (float4 within 16 cols), rowg = t>>2 (64 groups),
    // rows n = rowg + 64*i. Per wave-load: 16 rows x 64B lines, full use.
    int col = t & 3;
    int rowg = t >> 2;
    const float* Vb = V + (size_t)b * NN * HH + hc + col * 4;
    float4 A0 = {0, 0, 0, 0}, A1 = {0, 0, 0, 0};
#pragma unroll 8
    for (int i = 0; i < 32; i++) {
        int n = rowg + (i << 6);
        float4 x = *(const float4*)(Vb + (size_t)n * HH);
        float2 w = wls[n];
        A0.x += w.x * x.x; A0.y += w.x * x.y; A0.z += w.x * x.z; A0.w += w.x * x.w;
        A1.x += w.y * x.x; A1.y += w.y * x.y; A1.z += w.y * x.z; A1.w += w.y * x.w;
    }
    // in-wave reduce across the 16 rowgroups (offsets all multiples of 4)
#pragma unroll
    for (int off = 32; off >= 4; off >>= 1) {
        A0.x += __shfl_down(A0.x, off, 64); A0.y += __shfl_down(A0.y, off, 64);
        A0.z += __shfl_down(A0.z, off, 64); A0.w += __shfl_down(A0.w, off, 64);
        A1.x += __shfl_down(A1.x, off, 64); A1.y += __shfl_down(A1.y, off, 64);
        A1.z += __shfl_down(A1.z, off, 64); A1.w += __shfl_down(A1.w, off, 64);
    }
    int wv = t >> 6;
    if ((t & 63) < 4) {
        float* p = part[wv][t & 3];
        p[0] = A0.x; p[1] = A0.y; p[2] = A0.z; p[3] = A0.w;
        p[4] = A1.x; p[5] = A1.y; p[6] = A1.z; p[7] = A1.w;
    }
    __syncthreads();
    if (t < 4) {
        float4 r0 = {0, 0, 0, 0}, r1 = {0, 0, 0, 0};
#pragma unroll
        for (int w = 0; w < 4; w++) {
            const float* p = part[w][t];
            r0.x += p[0]; r0.y += p[1]; r0.z += p[2]; r0.w += p[3];
            r1.x += p[4]; r1.y += p[5]; r1.z += p[6]; r1.w += p[7];
        }
        *(float4*)(u0 + b * HH + hc + t * 4) = r0;
        *(float4*)(u1 + b * HH + hc + t * 4) = r1;
    }
}

// Kernel 3: attn_sum[b,o] = Wr0[o]·u0[b] + Wr1[o]·u1[b] + Wri[o]·Q[b],
// one wave per (b,o); weights are L2-resident (3 MB < 4 MB/XCD).
__global__ void k_out(const float* __restrict__ Q,
                      const float* __restrict__ Wr0,
                      const float* __restrict__ Wr1,
                      const float* __restrict__ Wri,
                      const float* __restrict__ u0,
                      const float* __restrict__ u1,
                      float* __restrict__ out) {
    int wave = (blockIdx.x * blockDim.x + threadIdx.x) >> 6;
    int lane = threadIdx.x & 63;
    if (wave >= BB * HH) return;
    int b = wave >> 9;
    int o = wave & 511;
    const float* q = Q + b * HH;
    const float* x0 = u0 + b * HH;
    const float* x1 = u1 + b * HH;
    const float* r0 = Wr0 + (size_t)o * HH;
    const float* r1 = Wr1 + (size_t)o * HH;
    const float* ri = Wri + (size_t)o * HH;
    float s = 0.0f;
#pragma unroll
    for (int part = 0; part < 2; part++) {
        int h = part * 256 + lane * 4;
        s += dot4(*(const float4*)(r0 + h), *(const float4*)(x0 + h));
        s += dot4(*(const float4*)(r1 + h), *(const float4*)(x1 + h));
        s += dot4(*(const float4*)(ri + h), *(const float4*)(q + h));
    }
#pragma unroll
    for (int off = 32; off > 0; off >>= 1) s += __shfl_down(s, off, 64);
    if (lane == 0) out[wave] = s;
}

extern "C" void kernel_launch(void* const* d_in, const int* in_sizes, int n_in,
                              void* d_out, int out_size, void* d_ws, size_t ws_size,
                              hipStream_t stream) {
    const float* Q = (const float*)d_in[0];
    const float* K = (const float*)d_in[1];
    const float* V = (const float*)d_in[2];
    const int* adj = (const int*)d_in[3];
    const int* s_mask = (const int*)d_in[4];
    const float* w_att = (const float*)d_in[5];
    // d_in[6] = b_att: unused — softmax invariant to per-row constants.
    const float* Wr0 = (const float*)d_in[7];
    const float* Wr1 = (const float*)d_in[8];
    const float* Wri = (const float*)d_in[9];

    float* out = (float*)d_out;
    float* attn = out;                // B*N floats (output 0)
    float* attn_sum = out + BB * NN;  // B*H floats (output 1)
    float* ws = (float*)d_ws;
    float* u0 = ws;
    float* u1 = ws + BB * HH;
    float* scores = ws + 2 * BB * HH;  // B*N raw scores scratch

    // 4 rows/wave -> BB*NN/4 waves -> /4 waves-per-block
    k_scores<<<(BB * NN) / 16, 256, 0, stream>>>(K, w_att, adj, scores);
    k_wsum<<<BB * (HH / CH), 256, 0, stream>>>(V, scores, attn, s_mask, u0, u1);
    k_out<<<(BB * HH) / 4, 256, 0, stream>>>(Q, Wr0, Wr1, Wri, u0, u1, attn_sum);
}

// Round 2
// 303.569 us; speedup vs baseline: 1.0333x; 1.0333x over previous
//
#include <hip/hip_runtime.h>

#define BB 32
#define NN 2048
#define HH 512

static __device__ __forceinline__ float dot4(float4 a, float4 b) {
    return a.x * b.x + a.y * b.y + a.z * b.z + a.w * b.w;
}

// ws layout (floats): u0[0,16384) u1[16384,32768) scores[32768,98304)
// u0/u1 accumulated via atomics in k_wsum -> zeroed up front in k_scores
// (harness poisons ws with 0xAA each iteration).

// Kernel 1: scores[b,n] = adj ? K[b,n]·wk : -1e30 (raw).
// Softmax is shift-invariant so Q·wq + b_att cancels exactly — dropped.
// 4 rows per wave: wk loaded once per wave, 8 independent K float4 loads
// in flight, fully sequential K traversal. Also zeroes u0/u1.
__global__ void k_scores(const float* __restrict__ K,
                         const float* __restrict__ w_att,
                         const int* __restrict__ adj,
                         float* __restrict__ scores,
                         float* __restrict__ ws) {
    int gtid = blockIdx.x * blockDim.x + threadIdx.x;
    if (gtid < 2 * BB * HH) ws[gtid] = 0.0f;  // zero u0/u1 for k_wsum atomics
    int wave = gtid >> 6;
    int lane = threadIdx.x & 63;
    const float* wk = w_att + HH;
    float4 a0 = *(const float4*)(wk + lane * 4);
    float4 a1 = *(const float4*)(wk + 256 + lane * 4);
    int row0 = wave * 4;  // wave < BB*NN/4 by grid construction
    const float* Kb = K + (size_t)row0 * HH + lane * 4;
    float4 k00 = *(const float4*)(Kb);
    float4 k01 = *(const float4*)(Kb + 256);
    float4 k10 = *(const float4*)(Kb + HH);
    float4 k11 = *(const float4*)(Kb + HH + 256);
    float4 k20 = *(const float4*)(Kb + 2 * HH);
    float4 k21 = *(const float4*)(Kb + 2 * HH + 256);
    float4 k30 = *(const float4*)(Kb + 3 * HH);
    float4 k31 = *(const float4*)(Kb + 3 * HH + 256);
    float s0 = dot4(k00, a0) + dot4(k01, a1);
    float s1 = dot4(k10, a0) + dot4(k11, a1);
    float s2 = dot4(k20, a0) + dot4(k21, a1);
    float s3 = dot4(k30, a0) + dot4(k31, a1);
#pragma unroll
    for (int off = 32; off > 0; off >>= 1) {
        s0 += __shfl_down(s0, off, 64);
        s1 += __shfl_down(s1, off, 64);
        s2 += __shfl_down(s2, off, 64);
        s3 += __shfl_down(s3, off, 64);
    }
    if (lane == 0) {
        int4 a = *(const int4*)(adj + row0);
        float4 o;
        o.x = a.x ? s0 : -1e30f;
        o.y = a.y ? s1 : -1e30f;
        o.z = a.z ? s2 : -1e30f;
        o.w = a.w ? s3 : -1e30f;
        *(float4*)(scores + row0) = o;
    }
}

// Kernel 2: (b, 64-row chunk) partition, contiguous full-row V reads.
// grid = B*32 = 1024 blocks x 256 threads (4 blocks/CU, 16 waves/CU).
// Softmax stats recomputed per block from L2-resident scores (8 KB),
// own chunk's weights staged in LDS, V accumulated unit-stride with
// unroll-8, halves combined through LDS, then 8 atomicAdds per thread.
#define ROWS 64
__global__ void k_wsum(const float* __restrict__ V,
                       const float* __restrict__ scores,
                       float* __restrict__ attn,
                       const int* __restrict__ s_mask,
                       float* __restrict__ u0,
                       float* __restrict__ u1) {
    int b = blockIdx.x >> 5;
    int n0 = (blockIdx.x & 31) * ROWS;
    int t = threadIdx.x;
    __shared__ float red[4];
    __shared__ float2 wls[ROWS];   // {w*sm, w*(1-sm)} per own row
    __shared__ float comb[1024];   // half-combine, 4 KB

    // --- softmax stats over the full batch row (vectorized, registers) ---
    const float* srow = scores + b * NN;
    float4 va = *(const float4*)(srow + t * 8);
    float4 vb = *(const float4*)(srow + t * 8 + 4);
    float m = fmaxf(fmaxf(fmaxf(va.x, va.y), fmaxf(va.z, va.w)),
                    fmaxf(fmaxf(vb.x, vb.y), fmaxf(vb.z, vb.w)));
#pragma unroll
    for (int off = 32; off > 0; off >>= 1) m = fmaxf(m, __shfl_xor(m, off, 64));
    if ((t & 63) == 0) red[t >> 6] = m;
    __syncthreads();
    float m4 = fmaxf(fmaxf(red[0], red[1]), fmaxf(red[2], red[3]));
    float sum = expf(va.x - m4) + expf(va.y - m4) + expf(va.z - m4) +
                expf(va.w - m4) + expf(vb.x - m4) + expf(vb.y - m4) +
                expf(vb.z - m4) + expf(vb.w - m4);
#pragma unroll
    for (int off = 32; off > 0; off >>= 1) sum += __shfl_xor(sum, off, 64);
    __syncthreads();  // red reuse
    if ((t & 63) == 0) red[t >> 6] = sum;
    __syncthreads();
    float inv = 1.0f / (red[0] + red[1] + red[2] + red[3]);

    // --- own chunk: attn output + weight staging ---
    if (t < ROWS) {
        float w = expf(srow[n0 + t] - m4) * inv;
        attn[b * NN + n0 + t] = w;  // output 0, normalized
        int sm = s_mask[b * NN + n0 + t];
        wls[t] = sm ? make_float2(w, 0.0f) : make_float2(0.0f, w);
    }
    __syncthreads();

    // --- weighted V accumulation, unit-stride rows ---
    int h4 = (t & 127) * 4;
    int half = t >> 7;  // rows [0,32) or [32,64) of the chunk
    const float* Vb = V + (size_t)(b * NN + n0 + half * 32) * HH + h4;
    float4 A0 = {0, 0, 0, 0}, A1 = {0, 0, 0, 0};
#pragma unroll 8
    for (int i = 0; i < 32; i++) {
        float4 x = *(const float4*)(Vb + (size_t)i * HH);
        float2 w = wls[half * 32 + i];
        A0.x += w.x * x.x; A0.y += w.x * x.y; A0.z += w.x * x.z; A0.w += w.x * x.w;
        A1.x += w.y * x.x; A1.y += w.y * x.y; A1.z += w.y * x.z; A1.w += w.y * x.w;
    }
    // combine the two halves through LDS -> halves the global atomics
    if (half == 1) {
        int i8 = (t - 128) * 8;
        comb[i8 + 0] = A0.x; comb[i8 + 1] = A0.y; comb[i8 + 2] = A0.z; comb[i8 + 3] = A0.w;
        comb[i8 + 4] = A1.x; comb[i8 + 5] = A1.y; comb[i8 + 6] = A1.z; comb[i8 + 7] = A1.w;
    }
    __syncthreads();
    if (half == 0) {
        int i8 = t * 8;
        A0.x += comb[i8 + 0]; A0.y += comb[i8 + 1]; A0.z += comb[i8 + 2]; A0.w += comb[i8 + 3];
        A1.x += comb[i8 + 4]; A1.y += comb[i8 + 5]; A1.z += comb[i8 + 6]; A1.w += comb[i8 + 7];
        float* p0 = u0 + b * HH + h4;
        float* p1 = u1 + b * HH + h4;
        atomicAdd(p0 + 0, A0.x); atomicAdd(p0 + 1, A0.y);
        atomicAdd(p0 + 2, A0.z); atomicAdd(p0 + 3, A0.w);
        atomicAdd(p1 + 0, A1.x); atomicAdd(p1 + 1, A1.y);
        atomicAdd(p1 + 2, A1.z); atomicAdd(p1 + 3, A1.w);
    }
}

// Kernel 3: attn_sum[b,o] = Wr0[o]·u0[b] + Wr1[o]·u1[b] + Wri[o]·Q[b],
// one wave per (b,o); weights are L2-resident (3 MB < 4 MB/XCD).
__global__ void k_out(const float* __restrict__ Q,
                      const float* __restrict__ Wr0,
                      const float* __restrict__ Wr1,
                      const float* __restrict__ Wri,
                      const float* __restrict__ u0,
                      const float* __restrict__ u1,
                      float* __restrict__ out) {
    int wave = (blockIdx.x * blockDim.x + threadIdx.x) >> 6;
    int lane = threadIdx.x & 63;
    if (wave >= BB * HH) return;
    int b = wave >> 9;
    int o = wave & 511;
    const float* q = Q + b * HH;
    const float* x0 = u0 + b * HH;
    const float* x1 = u1 + b * HH;
    const float* r0 = Wr0 + (size_t)o * HH;
    const float* r1 = Wr1 + (size_t)o * HH;
    const float* ri = Wri + (size_t)o * HH;
    float s = 0.0f;
#pragma unroll
    for (int part = 0; part < 2; part++) {
        int h = part * 256 + lane * 4;
        s += dot4(*(const float4*)(r0 + h), *(const float4*)(x0 + h));
        s += dot4(*(const float4*)(r1 + h), *(const float4*)(x1 + h));
        s += dot4(*(const float4*)(ri + h), *(const float4*)(q + h));
    }
#pragma unroll
    for (int off = 32; off > 0; off >>= 1) s += __shfl_down(s, off, 64);
    if (lane == 0) out[wave] = s;
}

extern "C" void kernel_launch(void* const* d_in, const int* in_sizes, int n_in,
                              void* d_out, int out_size, void* d_ws, size_t ws_size,
                              hipStream_t stream) {
    const float* Q = (const float*)d_in[0];
    const float* K = (const float*)d_in[1];
    const float* V = (const float*)d_in[2];
    const int* adj = (const int*)d_in[3];
    const int* s_mask = (const int*)d_in[4];
    const float* w_att = (const float*)d_in[5];
    // d_in[6] = b_att: unused — softmax invariant to per-row constants.
    const float* Wr0 = (const float*)d_in[7];
    const float* Wr1 = (const float*)d_in[8];
    const float* Wri = (const float*)d_in[9];

    float* out = (float*)d_out;
    float* attn = out;                // B*N floats (output 0)
    float* attn_sum = out + BB * NN;  // B*H floats (output 1)
    float* ws = (float*)d_ws;
    float* u0 = ws;
    float* u1 = ws + BB * HH;
    float* scores = ws + 2 * BB * HH;  // B*N raw scores scratch

    // 4 rows/wave -> BB*NN/4 waves -> 4 waves/block -> BB*NN/16 blocks
    k_scores<<<(BB * NN) / 16, 256, 0, stream>>>(K, w_att, adj, scores, ws);
    k_wsum<<<BB * 32, 256, 0, stream>>>(V, scores, attn, s_mask, u0, u1);
    k_out<<<(BB * HH) / 4, 256, 0, stream>>>(Q, Wr0, Wr1, Wri, u0, u1, attn_sum);
}